// Round 1
// baseline (128.700 us; speedup 1.0000x reference)
//
#include <hip/hip_runtime.h>

// Problem constants: B=16, L=1024, K=8, N=64, Hh=64
#define NBL 16384            // B*L
#define NGROUP 4096          // NBL / 4 (4 bl-slots per block iteration)

// workspace float offsets
#define WS_HPOW 0            // [NBL][8]
#define WS_YSUM 131072       // [NBL]
#define WS_AVG  147456       // [B][K] = 128

// output float offsets (outputs concatenated flat in return order)
#define OFF_V  0             // v_q   (16,1024,8,2)   262144
#define OFF_H  262144        // H_q   (16,1024,64,8,2) 16777216
#define OFF_Y  17039360      // y_q   (16,1024,64,2)  2097152
#define OFF_BT 19136512      // b_total (16,1024,8)
#define OFF_BY 19267584
#define OFF_BH 19398656
#define OFF_BD 19529728

// ---------------------------------------------------------------- kernel A
// per (b,l): h_power[k] = sum_{n,c} H^2 ; y_sum = sum_{n,c} y^2
__global__ __launch_bounds__(256) void k_power(const float* __restrict__ Hm,
                                               const float* __restrict__ ym,
                                               float* __restrict__ ws) {
  const int bl = blockIdx.x;
  const int t  = threadIdx.x;
  __shared__ float wsum[4][8];
  // thread t covers elements 4t..4t+3: k0=(2t)&7 (pairs c=0,1), k1=k0+1
  float4 h4 = *(const float4*)(Hm + bl * 1024 + t * 4);
  float s0 = h4.x * h4.x + h4.y * h4.y;
  float s1 = h4.z * h4.z + h4.w * h4.w;
  // reduce over the 16 lanes sharing (t&3): xor masks 4,8,16,32
  #pragma unroll
  for (int m = 4; m <= 32; m <<= 1) {
    s0 += __shfl_xor(s0, m, 64);
    s1 += __shfl_xor(s1, m, 64);
  }
  const int lane = t & 63, w = t >> 6;
  if (lane < 4) {
    wsum[w][2 * lane]     = s0;   // k0 = 2*(t&3)
    wsum[w][2 * lane + 1] = s1;   // k1 = k0+1
  }
  __syncthreads();
  if (t < 8)
    ws[WS_HPOW + bl * 8 + t] = wsum[0][t] + wsum[1][t] + wsum[2][t] + wsum[3][t];
  if (t < 64) {   // wave 0: y power
    float p = 0.0f;
    if (t < 32) {
      float4 v4 = *(const float4*)(ym + bl * 128 + t * 4);
      p = v4.x * v4.x + v4.y * v4.y + v4.z * v4.z + v4.w * v4.w;
    }
    #pragma unroll
    for (int m = 1; m <= 32; m <<= 1) p += __shfl_xor(p, m, 64);
    if (t == 0) ws[WS_YSUM + bl] = p;   // raw sum; log1p applied later
  }
}

// ---------------------------------------------------------------- kernel B
// avg_cp[b,k] = mean_l h_power[b,l,k]
__global__ __launch_bounds__(256) void k_avg(float* __restrict__ ws) {
  const int bk = blockIdx.x;        // b*8 + k
  const int b = bk >> 3, k = bk & 7;
  const int t = threadIdx.x;
  __shared__ float red[256];
  float p = 0.0f;
  for (int l = t; l < 1024; l += 256)
    p += ws[WS_HPOW + ((b << 10) + l) * 8 + k];
  red[t] = p;
  __syncthreads();
  for (int st = 128; st > 0; st >>= 1) {
    if (t < st) red[t] += red[t + st];
    __syncthreads();
  }
  if (t == 0) ws[WS_AVG + bk] = red[0] * (1.0f / 1024.0f);
}

// ---------------------------------------------------------------- helpers
__device__ inline void fma4(float4& acc, float4 a, float4 r0, float4 r1,
                            float4 r2, float4 r3) {
  acc.x = fmaf(a.x, r0.x, fmaf(a.y, r1.x, fmaf(a.z, r2.x, fmaf(a.w, r3.x, acc.x))));
  acc.y = fmaf(a.x, r0.y, fmaf(a.y, r1.y, fmaf(a.z, r2.y, fmaf(a.w, r3.y, acc.y))));
  acc.z = fmaf(a.x, r0.z, fmaf(a.y, r1.z, fmaf(a.z, r2.z, fmaf(a.w, r3.z, acc.z))));
  acc.w = fmaf(a.x, r0.w, fmaf(a.y, r1.w, fmaf(a.z, r2.w, fmaf(a.w, r3.w, acc.w))));
}

// one 64->64 layer: out[j4..j4+3] = relu(B + hin @ W), float4 LDS reads
__device__ inline void layer64(const float* hin, const float* W,
                               const float* B, float* hout, int j4) {
  float4 acc = *(const float4*)(B + j4);
  #pragma unroll
  for (int ic = 0; ic < 64; ic += 4) {
    float4 a = *(const float4*)(hin + ic);
    fma4(acc, a,
         *(const float4*)(W + (ic + 0) * 64 + j4),
         *(const float4*)(W + (ic + 1) * 64 + j4),
         *(const float4*)(W + (ic + 2) * 64 + j4),
         *(const float4*)(W + (ic + 3) * 64 + j4));
  }
  acc.x = fmaxf(acc.x, 0.0f); acc.y = fmaxf(acc.y, 0.0f);
  acc.z = fmaxf(acc.z, 0.0f); acc.w = fmaxf(acc.w, 0.0f);
  *(float4*)(hout + j4) = acc;
}

// LSQ params for a chosen branch j (0 = zero-output; encoded seff=1,qn=qp=0)
__device__ inline void qparams(int j, const float* __restrict__ svec, double fsize,
                               float& seff, float& qn, float& qp) {
  if (j == 0) { seff = 1.0f; qn = 0.0f; qp = 0.0f; return; }
  const int p = 1 << (4 * j - 1);            // 8,128,2048,32768
  const float qpv = (float)(p - 1);
  const float gscale = (float)(1.0 / sqrt(fsize * (double)(p - 1)));
  const float s  = svec[j - 1];
  const float sg = s * gscale;
  seff = sg + (s - sg);                      // literal forward of s_eff
  qn = -(float)p; qp = qpv;
}

__device__ inline float quantv(float x, float seff, float qn, float qp) {
  float xs = fminf(fmaxf(x / seff, qn), qp); // clip(x/s_eff, qn, qp)
  float r  = rintf(xs);                      // round half-even == jnp.round
  return (xs + (r - xs)) * seff;             // literal xq*s_eff
}

// ---------------------------------------------------------------- kernel C
// fused: features -> MLP -> gumbel-hard argmax -> b-links + quantize v,y,H
__global__ __launch_bounds__(512, 4) void k_main(
    const float* __restrict__ v,  const float* __restrict__ Hm,
    const float* __restrict__ ym, const float* __restrict__ snr,
    const float* __restrict__ gy, const float* __restrict__ gH,
    const float* __restrict__ gd,
    const float* __restrict__ W1, const float* __restrict__ B1,
    const float* __restrict__ W2, const float* __restrict__ B2,
    const float* __restrict__ W3, const float* __restrict__ B3,
    const float* __restrict__ Wy, const float* __restrict__ By,
    const float* __restrict__ Wh, const float* __restrict__ Bh,
    const float* __restrict__ Wd, const float* __restrict__ Bd,
    const float* __restrict__ sy, const float* __restrict__ sH,
    const float* __restrict__ sd,
    const float* __restrict__ ws, float* __restrict__ out) {

  __shared__ __align__(16) float sW1[9][64];
  __shared__ __align__(16) float sB1v[64];
  __shared__ __align__(16) float sW2[64][64];
  __shared__ __align__(16) float sB2v[64];
  __shared__ __align__(16) float sW3[64][64];
  __shared__ __align__(16) float sB3v[64];
  __shared__ __align__(16) float sWhT[15][68];   // heads transposed, rows 272B
  __shared__ float sBhv[16];
  __shared__ __align__(16) float sXF[4][8][12];  // features, rows 48B
  __shared__ __align__(16) float sHa[4][8][64];
  __shared__ __align__(16) float sHb[4][8][64];
  __shared__ float sHO[4][8][16];                // head outputs (15 used)
  __shared__ int   sJY[4], sJH[4][8], sJD[4][8];
  __shared__ float sYSe[4], sYSn[4], sYSp[4];
  __shared__ float sHSe[4][8], sHSn[4][8], sHSp[4][8];
  __shared__ float sDSe[4][8], sDSn[4][8], sDSp[4][8];

  const int t = threadIdx.x;
  // ---- stage weights to LDS (once per block)
  for (int i = t; i < 9 * 64; i += 512)  (&sW1[0][0])[i] = W1[i];
  for (int i = t; i < 64 * 64; i += 512) (&sW2[0][0])[i] = W2[i];
  for (int i = t; i < 64 * 64; i += 512) (&sW3[0][0])[i] = W3[i];
  if (t < 64) { sB1v[t] = B1[t]; sB2v[t] = B2[t]; sB3v[t] = B3[t]; }
  for (int i = t; i < 15 * 64; i += 512) {
    const int m = i >> 6, ii = i & 63;
    float val;
    if (m < 5)       val = Wy[ii * 5 + m];
    else if (m < 10) val = Wh[ii * 5 + (m - 5)];
    else             val = Wd[ii * 5 + (m - 10)];
    sWhT[m][ii] = val;
  }
  if (t < 15) sBhv[t] = (t < 5) ? By[t] : (t < 10) ? Bh[t - 5] : Bd[t - 10];
  __syncthreads();

  const int s  = t >> 7;           // bl-slot 0..3
  const int u  = t & 127;
  const int k8 = (u >> 4) & 7;     // k for layer phases
  const int j4 = (u & 15) * 4;     // output column group

  for (int g = blockIdx.x; g < NGROUP; g += gridDim.x) {
    const int bl0 = g << 2;
    const int bl  = bl0 + s;

    // ---- phase 0: features (8 threads per slot)
    if (u < 8) {
      const int k = u;
      float tot = 0.0f, hpk = 0.0f;
      #pragma unroll
      for (int kk = 0; kk < 8; kk++) {
        const float hv = ws[WS_HPOW + bl * 8 + kk];
        tot += hv;
        if (kk == k) hpk = hv;
      }
      const float vr = v[bl * 16 + 2 * k], vi = v[bl * 16 + 2 * k + 1];
      float* xf = &sXF[s][k][0];
      xf[0] = vr; xf[1] = vi;
      xf[2] = snr[bl * 8 + k];
      xf[3] = hpk;
      xf[4] = ws[WS_AVG + (bl >> 10) * 8 + k];
      xf[5] = log1pf(hpk / (tot - hpk + 1e-10f));
      xf[6] = log1pf(tot);
      xf[7] = log1pf(ws[WS_YSUM + bl]);
      xf[8] = sqrtf(vr * vr + vi * vi + 1e-10f);
    }
    __syncthreads();

    // ---- layer 1: 9 -> 64
    {
      float4 acc = *(const float4*)&sB1v[j4];
      const float* xr = &sXF[s][k8][0];
      const float4 a0 = *(const float4*)xr;
      const float4 a1 = *(const float4*)(xr + 4);
      const float a8  = xr[8];
      fma4(acc, a0, *(const float4*)&sW1[0][j4], *(const float4*)&sW1[1][j4],
                    *(const float4*)&sW1[2][j4], *(const float4*)&sW1[3][j4]);
      fma4(acc, a1, *(const float4*)&sW1[4][j4], *(const float4*)&sW1[5][j4],
                    *(const float4*)&sW1[6][j4], *(const float4*)&sW1[7][j4]);
      const float4 w8 = *(const float4*)&sW1[8][j4];
      acc.x = fmaf(a8, w8.x, acc.x); acc.y = fmaf(a8, w8.y, acc.y);
      acc.z = fmaf(a8, w8.z, acc.z); acc.w = fmaf(a8, w8.w, acc.w);
      acc.x = fmaxf(acc.x, 0.0f); acc.y = fmaxf(acc.y, 0.0f);
      acc.z = fmaxf(acc.z, 0.0f); acc.w = fmaxf(acc.w, 0.0f);
      *(float4*)&sHa[s][k8][j4] = acc;
    }
    __syncthreads();
    // ---- layer 2 and 3
    layer64(&sHa[s][k8][0], &sW2[0][0], sB2v, &sHb[s][k8][0], j4);
    __syncthreads();
    layer64(&sHb[s][k8][0], &sW3[0][0], sB3v, &sHa[s][k8][0], j4);
    __syncthreads();

    // ---- heads: 15 outputs per (s,k); h3 is in sHa
    if (u < 120) {
      const int kh = u / 15, m = u % 15;
      float acc = sBhv[m];
      const float* hr = &sHa[s][kh][0];
      const float* wr = &sWhT[m][0];
      #pragma unroll
      for (int ic = 0; ic < 64; ic += 4) {
        const float4 a = *(const float4*)(hr + ic);
        const float4 w = *(const float4*)(wr + ic);
        acc = fmaf(a.x, w.x, fmaf(a.y, w.y, fmaf(a.z, w.z, fmaf(a.w, w.w, acc))));
      }
      sHO[s][kh][m] = acc;
    }
    __syncthreads();

    // ---- decisions (gumbel-hard forward == first-argmax of logits+g)
    if (u < 8) {                       // w_H per (bl,k)
      const int k = u;
      const float* gg = gH + (bl * 8 + k) * 5;
      float bv = sHO[s][k][5] + gg[0]; int bj = 0;
      #pragma unroll
      for (int c = 1; c < 5; c++) {
        const float lv = sHO[s][k][5 + c] + gg[c];
        if (lv > bv) { bv = lv; bj = c; }
      }
      sJH[s][k] = bj;
      qparams(bj, sH, 16777216.0, sHSe[s][k], sHSn[s][k], sHSp[s][k]);
    } else if (u < 16) {               // w_d per (bl,k)
      const int k = u - 8;
      const float* gg = gd + (bl * 8 + k) * 5;
      float bv = sHO[s][k][10] + gg[0]; int bj = 0;
      #pragma unroll
      for (int c = 1; c < 5; c++) {
        const float lv = sHO[s][k][10 + c] + gg[c];
        if (lv > bv) { bv = lv; bj = c; }
      }
      sJD[s][k] = bj;
      qparams(bj, sd, 262144.0, sDSe[s][k], sDSn[s][k], sDSp[s][k]);
    } else if (u == 16) {              // w_y per bl (mean over k first)
      float ls[5];
      #pragma unroll
      for (int c = 0; c < 5; c++) {
        float acc = 0.0f;
        #pragma unroll
        for (int k = 0; k < 8; k++) acc += sHO[s][k][c];
        ls[c] = acc * 0.125f;
      }
      const float* gg = gy + bl * 5;
      float bv = ls[0] + gg[0]; int bj = 0;
      #pragma unroll
      for (int c = 1; c < 5; c++) {
        const float lv = ls[c] + gg[c];
        if (lv > bv) { bv = lv; bj = c; }
      }
      sJY[s] = bj;
      qparams(bj, sy, 2097152.0, sYSe[s], sYSn[s], sYSp[s]);
    }
    __syncthreads();

    // ---- b-links + v quant + y quant
    if (u < 8) {
      const int k = u;
      const float by_ = 64.0f  * (float)sJY[s];      // 16 * (4*j)
      const float bH_ = 512.0f * (float)sJH[s][k];   // 128 * (4*j)
      const float bd_ = 8.0f   * (float)sJD[s][k];   // 2 * (4*j)
      const int oi = bl * 8 + k;
      out[OFF_BT + oi] = by_ + bH_ + bd_;
      out[OFF_BY + oi] = by_;
      out[OFF_BH + oi] = bH_;
      out[OFF_BD + oi] = bd_;
    } else if (u >= 24 && u < 32) {    // v_q: 8 threads x float2 (one k each)
      const int m = u - 24;
      const float2 xv = *(const float2*)(v + bl * 16 + 2 * m);
      float2 r;
      r.x = quantv(xv.x, sDSe[s][m], sDSn[s][m], sDSp[s][m]);
      r.y = quantv(xv.y, sDSe[s][m], sDSn[s][m], sDSp[s][m]);
      *(float2*)(out + OFF_V + bl * 16 + 2 * m) = r;
    } else if (u >= 32 && u < 64) {    // y_q: 32 threads x float4
      const int m = u - 32;
      const float4 xv = *(const float4*)(ym + bl * 128 + 4 * m);
      float4 r;
      r.x = quantv(xv.x, sYSe[s], sYSn[s], sYSp[s]);
      r.y = quantv(xv.y, sYSe[s], sYSn[s], sYSp[s]);
      r.z = quantv(xv.z, sYSe[s], sYSn[s], sYSp[s]);
      r.w = quantv(xv.w, sYSe[s], sYSn[s], sYSp[s]);
      *(float4*)(out + OFF_Y + bl * 128 + 4 * m) = r;
    }

    // ---- H quant: whole block streams the group's 4096 floats
    for (int c = t; c < 1024; c += 512) {
      const int s2 = c >> 8;
      const int k0 = (2 * c) & 7;      // even; pair (k0, k0+1)
      const float4 xh = *(const float4*)(Hm + bl0 * 1024 + 4 * c);
      float4 r;
      r.x = quantv(xh.x, sHSe[s2][k0],     sHSn[s2][k0],     sHSp[s2][k0]);
      r.y = quantv(xh.y, sHSe[s2][k0],     sHSn[s2][k0],     sHSp[s2][k0]);
      r.z = quantv(xh.z, sHSe[s2][k0 + 1], sHSn[s2][k0 + 1], sHSp[s2][k0 + 1]);
      r.w = quantv(xh.w, sHSe[s2][k0 + 1], sHSn[s2][k0 + 1], sHSp[s2][k0 + 1]);
      *(float4*)(out + OFF_H + bl0 * 1024 + 4 * c) = r;
    }
    // no barrier needed: next phase-0 writes only sXF (not touched above);
    // the barrier after phase-0 orders everything else.
  }
}

// ---------------------------------------------------------------- launch
extern "C" void kernel_launch(void* const* d_in, const int* in_sizes, int n_in,
                              void* d_out, int out_size, void* d_ws, size_t ws_size,
                              hipStream_t stream) {
  (void)in_sizes; (void)n_in; (void)out_size; (void)ws_size;
  const float* v   = (const float*)d_in[0];
  const float* Hm  = (const float*)d_in[1];
  const float* ym  = (const float*)d_in[2];
  const float* snr = (const float*)d_in[3];
  const float* gy  = (const float*)d_in[4];
  const float* gH  = (const float*)d_in[5];
  const float* gd  = (const float*)d_in[6];
  const float* W1  = (const float*)d_in[7];
  const float* B1  = (const float*)d_in[8];
  const float* W2  = (const float*)d_in[9];
  const float* B2  = (const float*)d_in[10];
  const float* W3  = (const float*)d_in[11];
  const float* B3  = (const float*)d_in[12];
  const float* Wy  = (const float*)d_in[13];
  const float* By  = (const float*)d_in[14];
  const float* Wh  = (const float*)d_in[15];
  const float* Bh  = (const float*)d_in[16];
  const float* Wd  = (const float*)d_in[17];
  const float* Bd  = (const float*)d_in[18];
  const float* sy  = (const float*)d_in[19];
  const float* sH  = (const float*)d_in[20];
  const float* sd  = (const float*)d_in[21];
  float* out = (float*)d_out;
  float* ws  = (float*)d_ws;

  k_power<<<NBL, 256, 0, stream>>>(Hm, ym, ws);
  k_avg<<<128, 256, 0, stream>>>(ws);
  k_main<<<512, 512, 0, stream>>>(v, Hm, ym, snr, gy, gH, gd,
                                  W1, B1, W2, B2, W3, B3,
                                  Wy, By, Wh, Bh, Wd, Bd,
                                  sy, sH, sd, ws, out);
}

// Round 2
// 79.429 us; speedup vs baseline: 1.6203x; 1.6203x over previous
//
#include <hip/hip_runtime.h>

// Problem constants: B=16, L=1024, K=8, N=64, Hh=64
#define NBL 16384
#define SL 8                 // bl-slots per block iteration
#define NG 2048              // NBL / SL
#define GRID 512             // 2 blocks/CU -> 4 iterations per block

// workspace float offsets
#define WS_HPOW 0            // [NBL][8]
#define WS_YSUM 131072       // [NBL]
#define WS_AVG  147456       // [B][K]

// output float offsets
#define OFF_V  0
#define OFF_H  262144
#define OFF_Y  17039360
#define OFF_BT 19136512
#define OFF_BY 19267584
#define OFF_BH 19398656
#define OFF_BD 19529728

// ---------------------------------------------------------------- kernel A
__global__ __launch_bounds__(256) void k_power(const float* __restrict__ Hm,
                                               const float* __restrict__ ym,
                                               float* __restrict__ ws) {
  const int bl = blockIdx.x;
  const int t  = threadIdx.x;
  __shared__ float wsum[4][8];
  float4 h4 = *(const float4*)(Hm + bl * 1024 + t * 4);
  float s0 = h4.x * h4.x + h4.y * h4.y;
  float s1 = h4.z * h4.z + h4.w * h4.w;
  #pragma unroll
  for (int m = 4; m <= 32; m <<= 1) {
    s0 += __shfl_xor(s0, m, 64);
    s1 += __shfl_xor(s1, m, 64);
  }
  const int lane = t & 63, w = t >> 6;
  if (lane < 4) {
    wsum[w][2 * lane]     = s0;
    wsum[w][2 * lane + 1] = s1;
  }
  __syncthreads();
  if (t < 8)
    ws[WS_HPOW + bl * 8 + t] = wsum[0][t] + wsum[1][t] + wsum[2][t] + wsum[3][t];
  if (t < 64) {
    float p = 0.0f;
    if (t < 32) {
      float4 v4 = *(const float4*)(ym + bl * 128 + t * 4);
      p = v4.x * v4.x + v4.y * v4.y + v4.z * v4.z + v4.w * v4.w;
    }
    #pragma unroll
    for (int m = 1; m <= 32; m <<= 1) p += __shfl_xor(p, m, 64);
    if (t == 0) ws[WS_YSUM + bl] = p;
  }
}

// ---------------------------------------------------------------- kernel B
__global__ __launch_bounds__(256) void k_avg(float* __restrict__ ws) {
  const int bk = blockIdx.x;
  const int b = bk >> 3, k = bk & 7;
  const int t = threadIdx.x;
  __shared__ float red[256];
  float p = 0.0f;
  for (int l = t; l < 1024; l += 256)
    p += ws[WS_HPOW + ((b << 10) + l) * 8 + k];
  red[t] = p;
  __syncthreads();
  for (int st = 128; st > 0; st >>= 1) {
    if (t < st) red[t] += red[t + st];
    __syncthreads();
  }
  if (t == 0) ws[WS_AVG + bk] = red[0] * (1.0f / 1024.0f);
}

// ---------------------------------------------------------------- helpers
__device__ inline void fma4(float4& acc, float4 a, float4 r0, float4 r1,
                            float4 r2, float4 r3) {
  acc.x = fmaf(a.x, r0.x, fmaf(a.y, r1.x, fmaf(a.z, r2.x, fmaf(a.w, r3.x, acc.x))));
  acc.y = fmaf(a.x, r0.y, fmaf(a.y, r1.y, fmaf(a.z, r2.y, fmaf(a.w, r3.y, acc.y))));
  acc.z = fmaf(a.x, r0.z, fmaf(a.y, r1.z, fmaf(a.z, r2.z, fmaf(a.w, r3.z, acc.z))));
  acc.w = fmaf(a.x, r0.w, fmaf(a.y, r1.w, fmaf(a.z, r2.w, fmaf(a.w, r3.w, acc.w))));
}

__device__ inline float4 relu4(float4 a) {
  a.x = fmaxf(a.x, 0.0f); a.y = fmaxf(a.y, 0.0f);
  a.z = fmaxf(a.z, 0.0f); a.w = fmaxf(a.w, 0.0f);
  return a;
}

// 64->64 layer for TWO sites sharing one weight-column read
__device__ inline void layer64x2(const float* __restrict__ A0,
                                 const float* __restrict__ A1,
                                 const float* __restrict__ W,
                                 const float* __restrict__ Bv,
                                 float* __restrict__ O0, float* __restrict__ O1,
                                 int j4) {
  float4 acc0 = *(const float4*)(Bv + j4);
  float4 acc1 = acc0;
  #pragma unroll
  for (int ic = 0; ic < 64; ic += 4) {
    const float4 w0 = *(const float4*)(W + (ic + 0) * 64 + j4);
    const float4 w1 = *(const float4*)(W + (ic + 1) * 64 + j4);
    const float4 w2 = *(const float4*)(W + (ic + 2) * 64 + j4);
    const float4 w3 = *(const float4*)(W + (ic + 3) * 64 + j4);
    const float4 a0 = *(const float4*)(A0 + ic);
    const float4 a1 = *(const float4*)(A1 + ic);
    fma4(acc0, a0, w0, w1, w2, w3);
    fma4(acc1, a1, w0, w1, w2, w3);
  }
  acc0 = relu4(acc0); acc1 = relu4(acc1);
  *(float4*)(O0 + j4) = acc0;
  *(float4*)(O1 + j4) = acc1;
}

// LSQ params for chosen branch j; j==0 encodes the zero branch
__device__ inline void qparams4(int j, const float* __restrict__ sv,
                                double fsize, float* __restrict__ dst) {
  float se = 1.0f, qn = 0.0f, qp = 0.0f;
  if (j > 0) {
    const int p = 1 << (4 * j - 1);            // 8,128,2048,32768
    const float gscale = (float)(1.0 / sqrt(fsize * (double)(p - 1)));
    const float s  = sv[j - 1];
    const float sg = s * gscale;
    se = sg + (s - sg);                        // literal forward of s_eff
    qn = -(float)p; qp = (float)(p - 1);
  }
  dst[0] = se; dst[1] = qn; dst[2] = qp; dst[3] = 0.0f;
}

__device__ inline float quantv(float x, float seff, float qn, float qp) {
  float xs = fminf(fmaxf(x / seff, qn), qp);
  float r  = rintf(xs);
  return (xs + (r - xs)) * seff;
}

__device__ inline void do_feat(const float* __restrict__ v,
                               const float* __restrict__ snr,
                               const float* __restrict__ ws,
                               float* __restrict__ sXF,
                               int bl, int s, int k) {
  float tot = 0.0f, hpk = 0.0f;
  #pragma unroll
  for (int kk = 0; kk < 8; kk++) {
    const float hv = ws[WS_HPOW + bl * 8 + kk];
    tot += hv;
    if (kk == k) hpk = hv;
  }
  const float vr = v[bl * 16 + 2 * k], vi = v[bl * 16 + 2 * k + 1];
  float* xf = sXF + (s * 8 + k) * 12;
  xf[0] = vr; xf[1] = vi;
  xf[2] = snr[bl * 8 + k];
  xf[3] = hpk;
  xf[4] = ws[WS_AVG + (bl >> 10) * 8 + k];
  xf[5] = log1pf(hpk / (tot - hpk + 1e-10f));
  xf[6] = log1pf(tot);
  xf[7] = log1pf(ws[WS_YSUM + bl]);
  xf[8] = sqrtf(vr * vr + vi * vi + 1e-10f);
}

// ---------------------------------------------------------------- kernel C
__global__ __launch_bounds__(512, 4) void k_main(
    const float* __restrict__ v,  const float* __restrict__ Hm,
    const float* __restrict__ ym, const float* __restrict__ snr,
    const float* __restrict__ gy, const float* __restrict__ gH,
    const float* __restrict__ gd,
    const float* __restrict__ W1, const float* __restrict__ B1,
    const float* __restrict__ W2, const float* __restrict__ B2,
    const float* __restrict__ W3, const float* __restrict__ B3,
    const float* __restrict__ Wy, const float* __restrict__ By,
    const float* __restrict__ Wh, const float* __restrict__ Bh,
    const float* __restrict__ Wd, const float* __restrict__ Bd,
    const float* __restrict__ sy, const float* __restrict__ sH,
    const float* __restrict__ sd,
    const float* __restrict__ ws, float* __restrict__ out) {

  __shared__ __align__(16) float sW1[9][64];
  __shared__ __align__(16) float sW2[64][64];
  __shared__ __align__(16) float sW3[64][64];
  __shared__ __align__(16) float sWhT[15][68];   // head weights, transposed
  __shared__ float sB1v[64], sB2v[64], sB3v[64], sBhv[16];
  __shared__ __align__(16) float sHa[8][8][68];  // act buf A (pad 68: k-stride 4 banks)
  __shared__ __align__(16) float sHb[8][8][68];  // act buf B; aliased: sXF, sHO
  __shared__ int sJY[8], sJH[8][8], sJD[8][8];
  __shared__ __align__(16) float sQY[8][4];      // {seff,qn,qp,-}
  __shared__ __align__(16) float sQH[8][8][4];
  __shared__ __align__(16) float sQD[8][8][4];

  // overlays into sHb (dead between L3-read and L2-write of next iter):
  float* const sXF = &sHb[0][0][0];              // [64][12], floats 0..767
  float* const sHO = &sHb[0][0][0] + 1024;       // [64][17], floats 1024..2111

  const int t = threadIdx.x;
  // ---- stage weights (once per block)
  for (int i = t; i < 9 * 64; i += 512)  (&sW1[0][0])[i] = W1[i];
  for (int i = t; i < 64 * 64; i += 512) (&sW2[0][0])[i] = W2[i];
  for (int i = t; i < 64 * 64; i += 512) (&sW3[0][0])[i] = W3[i];
  if (t < 64) { sB1v[t] = B1[t]; sB2v[t] = B2[t]; sB3v[t] = B3[t]; }
  for (int i = t; i < 15 * 64; i += 512) {
    const int m = i >> 6, ii = i & 63;
    float val;
    if (m < 5)       val = Wy[ii * 5 + m];
    else if (m < 10) val = Wh[ii * 5 + (m - 5)];
    else             val = Wd[ii * 5 + (m - 10)];
    sWhT[m][ii] = val;
  }
  if (t < 15) sBhv[t] = (t < 5) ? By[t] : (t < 10) ? Bh[t - 5] : Bd[t - 10];
  // ---- features for the first group
  if (t < 64) do_feat(v, snr, ws, sXF, blockIdx.x * SL + (t >> 3), t >> 3, t & 7);
  __syncthreads();

  const int j4 = (t & 15) * 4;     // output column group
  const int k8 = (t >> 4) & 7;     // k
  const int sp = t >> 7;           // slot-pair id 0..3 -> slots sp, sp+4

  for (int g = blockIdx.x; g < NG; g += GRID) {
    const int bl0 = g * SL;

    // ---- layer 1: 9 -> 64 (two slots per thread, shared weights)
    {
      float4 acc0 = *(const float4*)&sB1v[j4];
      float4 acc1 = acc0;
      const float* x0 = sXF + (sp * 8 + k8) * 12;
      const float* x1 = sXF + ((sp + 4) * 8 + k8) * 12;
      #pragma unroll
      for (int r = 0; r < 9; r++) {
        const float4 w = *(const float4*)&sW1[r][j4];
        const float a0 = x0[r], a1 = x1[r];
        acc0.x = fmaf(a0, w.x, acc0.x); acc0.y = fmaf(a0, w.y, acc0.y);
        acc0.z = fmaf(a0, w.z, acc0.z); acc0.w = fmaf(a0, w.w, acc0.w);
        acc1.x = fmaf(a1, w.x, acc1.x); acc1.y = fmaf(a1, w.y, acc1.y);
        acc1.z = fmaf(a1, w.z, acc1.z); acc1.w = fmaf(a1, w.w, acc1.w);
      }
      acc0 = relu4(acc0); acc1 = relu4(acc1);
      *(float4*)&sHa[sp][k8][j4]     = acc0;
      *(float4*)&sHa[sp + 4][k8][j4] = acc1;
    }
    __syncthreads();
    // ---- layer 2: sHa -> sHb
    layer64x2(&sHa[sp][k8][0], &sHa[sp + 4][k8][0], &sW2[0][0], sB2v,
              &sHb[sp][k8][0], &sHb[sp + 4][k8][0], j4);
    __syncthreads();
    // ---- layer 3: sHb -> sHa
    layer64x2(&sHb[sp][k8][0], &sHb[sp + 4][k8][0], &sW3[0][0], sB3v,
              &sHa[sp][k8][0], &sHa[sp + 4][k8][0], j4);
    __syncthreads();

    // ---- heads: 15 logits per site (two slots per thread)
    if (t < 480) {
      const int q = t / 15, m = t - q * 15;
      const int kh = q & 7, sq = q >> 3;
      const float* h0 = &sHa[sq][kh][0];
      const float* h1 = &sHa[sq + 4][kh][0];
      const float* wr = &sWhT[m][0];
      float acc0 = sBhv[m], acc1 = acc0;
      #pragma unroll
      for (int ic = 0; ic < 64; ic += 4) {
        const float4 w  = *(const float4*)(wr + ic);
        const float4 a0 = *(const float4*)(h0 + ic);
        const float4 a1 = *(const float4*)(h1 + ic);
        acc0 = fmaf(a0.x, w.x, fmaf(a0.y, w.y, fmaf(a0.z, w.z, fmaf(a0.w, w.w, acc0))));
        acc1 = fmaf(a1.x, w.x, fmaf(a1.y, w.y, fmaf(a1.z, w.z, fmaf(a1.w, w.w, acc1))));
      }
      sHO[(sq * 8 + kh) * 17 + m] = acc0;
      sHO[((sq + 4) * 8 + kh) * 17 + m] = acc1;
    }
    __syncthreads();

    // ---- decisions (gumbel-hard forward == first-argmax of logits+g)
    if (t < 64) {                       // w_H, site t
      const int s = t >> 3, k = t & 7;
      const float* ho = sHO + t * 17;
      const float* gg = gH + ((bl0 + s) * 8 + k) * 5;
      float bv = ho[5] + gg[0]; int bj = 0;
      #pragma unroll
      for (int c = 1; c < 5; c++) {
        const float lv = ho[5 + c] + gg[c];
        if (lv > bv) { bv = lv; bj = c; }
      }
      sJH[s][k] = bj;
      qparams4(bj, sH, 16777216.0, &sQH[s][k][0]);
    } else if (t < 128) {               // w_d, site t-64
      const int u = t - 64, s = u >> 3, k = u & 7;
      const float* ho = sHO + u * 17;
      const float* gg = gd + ((bl0 + s) * 8 + k) * 5;
      float bv = ho[10] + gg[0]; int bj = 0;
      #pragma unroll
      for (int c = 1; c < 5; c++) {
        const float lv = ho[10 + c] + gg[c];
        if (lv > bv) { bv = lv; bj = c; }
      }
      sJD[s][k] = bj;
      qparams4(bj, sd, 262144.0, &sQD[s][k][0]);
    } else if (t < 136) {               // w_y, slot t-128 (mean over k)
      const int s = t - 128;
      float ls[5];
      #pragma unroll
      for (int c = 0; c < 5; c++) {
        float acc = 0.0f;
        #pragma unroll
        for (int k = 0; k < 8; k++) acc += sHO[(s * 8 + k) * 17 + c];
        ls[c] = acc * 0.125f;
      }
      const float* gg = gy + (bl0 + s) * 5;
      float bv = ls[0] + gg[0]; int bj = 0;
      #pragma unroll
      for (int c = 1; c < 5; c++) {
        const float lv = ls[c] + gg[c];
        if (lv > bv) { bv = lv; bj = c; }
      }
      sJY[s] = bj;
      qparams4(bj, sy, 2097152.0, &sQY[s][0]);
    }
    __syncthreads();

    // ---- phase Q: b-links, v_q, y_q, next-iter features, H_q
    if (t < 64) {                       // b-links, site t
      const int s = t >> 3, k = t & 7;
      const int oi = (bl0 + s) * 8 + k;
      const float by_ = 64.0f  * (float)sJY[s];
      const float bH_ = 512.0f * (float)sJH[s][k];
      const float bd_ = 8.0f   * (float)sJD[s][k];
      out[OFF_BT + oi] = by_ + bH_ + bd_;
      out[OFF_BY + oi] = by_;
      out[OFF_BH + oi] = bH_;
      out[OFF_BD + oi] = bd_;
    } else if (t < 128) {               // v_q, site t-64
      const int u = t - 64, s = u >> 3, k = u & 7, bl = bl0 + s;
      const float4 qd = *(const float4*)&sQD[s][k][0];
      const float2 xv = *(const float2*)(v + bl * 16 + 2 * k);
      float2 r;
      r.x = quantv(xv.x, qd.x, qd.y, qd.z);
      r.y = quantv(xv.y, qd.x, qd.y, qd.z);
      *(float2*)(out + OFF_V + bl * 16 + 2 * k) = r;
    } else if (t < 384) {               // y_q: 256 threads x float4
      const int u = t - 128, s = u >> 5, m = u & 31, bl = bl0 + s;
      const float4 qy = *(const float4*)&sQY[s][0];
      const float4 xv = *(const float4*)(ym + bl * 128 + 4 * m);
      float4 r;
      r.x = quantv(xv.x, qy.x, qy.y, qy.z);
      r.y = quantv(xv.y, qy.x, qy.y, qy.z);
      r.z = quantv(xv.z, qy.x, qy.y, qy.z);
      r.w = quantv(xv.w, qy.x, qy.y, qy.z);
      *(float4*)(out + OFF_Y + bl * 128 + 4 * m) = r;
    } else if (t < 448) {               // features for next group
      const int gN = g + GRID;
      if (gN < NG) {
        const int u = t - 384;
        do_feat(v, snr, ws, sXF, gN * SL + (u >> 3), u >> 3, u & 7);
      }
    }
    // H_q: all 512 threads, 8192 floats (8 slots x 1024)
    #pragma unroll
    for (int c4 = 0; c4 < 4; c4++) {
      const int c  = t + c4 * 512;       // float4 index within group
      const int s2 = c >> 8;
      const int cc = c & 255;
      const int k0 = (2 * cc) & 7;       // even; elems are pairs (k0,k0+1)
      const float4 qa = *(const float4*)&sQH[s2][k0][0];
      const float4 qb = *(const float4*)&sQH[s2][k0 + 1][0];
      const float4 xh = *(const float4*)(Hm + bl0 * 1024 + 4 * c);
      float4 r;
      r.x = quantv(xh.x, qa.x, qa.y, qa.z);
      r.y = quantv(xh.y, qa.x, qa.y, qa.z);
      r.z = quantv(xh.z, qb.x, qb.y, qb.z);
      r.w = quantv(xh.w, qb.x, qb.y, qb.z);
      *(float4*)(out + OFF_H + bl0 * 1024 + 4 * c) = r;
    }
    __syncthreads();
  }
}

// ---------------------------------------------------------------- launch
extern "C" void kernel_launch(void* const* d_in, const int* in_sizes, int n_in,
                              void* d_out, int out_size, void* d_ws, size_t ws_size,
                              hipStream_t stream) {
  (void)in_sizes; (void)n_in; (void)out_size; (void)ws_size;
  const float* v   = (const float*)d_in[0];
  const float* Hm  = (const float*)d_in[1];
  const float* ym  = (const float*)d_in[2];
  const float* snr = (const float*)d_in[3];
  const float* gy  = (const float*)d_in[4];
  const float* gH  = (const float*)d_in[5];
  const float* gd  = (const float*)d_in[6];
  const float* W1  = (const float*)d_in[7];
  const float* B1  = (const float*)d_in[8];
  const float* W2  = (const float*)d_in[9];
  const float* B2  = (const float*)d_in[10];
  const float* W3  = (const float*)d_in[11];
  const float* B3  = (const float*)d_in[12];
  const float* Wy  = (const float*)d_in[13];
  const float* By  = (const float*)d_in[14];
  const float* Wh  = (const float*)d_in[15];
  const float* Bh  = (const float*)d_in[16];
  const float* Wd  = (const float*)d_in[17];
  const float* Bd  = (const float*)d_in[18];
  const float* sy  = (const float*)d_in[19];
  const float* sH  = (const float*)d_in[20];
  const float* sd  = (const float*)d_in[21];
  float* out = (float*)d_out;
  float* ws  = (float*)d_ws;

  k_power<<<NBL, 256, 0, stream>>>(Hm, ym, ws);
  k_avg<<<128, 256, 0, stream>>>(ws);
  k_main<<<GRID, 512, 0, stream>>>(v, Hm, ym, snr, gy, gH, gd,
                                   W1, B1, W2, B2, W3, B3,
                                   Wy, By, Wh, Bh, Wd, Bd,
                                   sy, sH, sd, ws, out);
}